// Round 7
// baseline (6594.686 us; speedup 1.0000x reference)
//
#include <hip/hip_runtime.h>
#include <math.h>

#define NN 100000
#define DD 128
#define CC 16
#define SS 16
#define EE 3200000
#define KK 64
#define NIT 4
#define CNT_STRIDE 32      // pad class counters 128B apart
#define RUNS 64            // stage-A wave-slices per class
#define GRID 1024          // persistent blocks: 4 blocks/CU (LDS 37.4KB*4 <= 160KB)
#define NGRP 64            // barrier groups of 16 blocks
#define CHUNK 192          // nodes per candidate chunk
#define NCH ((NN + CHUNK - 1) / CHUNK)   // 521 chunks
#define INF_STAMP 0x7fffffff

typedef unsigned long long ull;

// ---- barrier state: device globals (zero-init, not in poisoned d_ws) ----
// g_gen/g_ggen monotone across graph replays (sense read before arrival);
// g_cnt and group counters return to 0 after every barrier.
__device__ int g_grp[NGRP * 32];   // arrival counters, 128B apart
__device__ int g_ggen[NGRP * 32];  // per-group release gens, 128B apart
__device__ int g_cnt = 0;
__device__ int g_gen = 0;

__device__ __forceinline__ void gridbar() {
    __syncthreads();
    if (threadIdx.x == 0) {
        int g = __hip_atomic_load(&g_gen, __ATOMIC_RELAXED, __HIP_MEMORY_SCOPE_AGENT);
        int grp = blockIdx.x >> 4;
        int a = __hip_atomic_fetch_add(&g_grp[grp * 32], 1, __ATOMIC_ACQ_REL,
                                       __HIP_MEMORY_SCOPE_AGENT);
        if (a == 15) {                      // group leader
            __hip_atomic_store(&g_grp[grp * 32], 0, __ATOMIC_RELAXED,
                               __HIP_MEMORY_SCOPE_AGENT);
            int b = __hip_atomic_fetch_add(&g_cnt, 1, __ATOMIC_ACQ_REL,
                                           __HIP_MEMORY_SCOPE_AGENT);
            if (b == NGRP - 1) {
                __hip_atomic_store(&g_cnt, 0, __ATOMIC_RELAXED,
                                   __HIP_MEMORY_SCOPE_AGENT);
                __hip_atomic_fetch_add(&g_gen, 1, __ATOMIC_RELEASE,
                                       __HIP_MEMORY_SCOPE_AGENT);
            }
            while (__hip_atomic_load(&g_gen, __ATOMIC_ACQUIRE,
                                     __HIP_MEMORY_SCOPE_AGENT) == g)
                __builtin_amdgcn_s_sleep(2);       // only 64 pollers on this line
            __hip_atomic_store(&g_ggen[grp * 32], g + 1, __ATOMIC_RELEASE,
                               __HIP_MEMORY_SCOPE_AGENT);
        } else {
            while (__hip_atomic_load(&g_ggen[grp * 32], __ATOMIC_ACQUIRE,
                                     __HIP_MEMORY_SCOPE_AGENT) <= g)
                __builtin_amdgcn_s_sleep(2);       // <=15 pollers per line
        }
    }
    __syncthreads();
}

// order-preserving double -> uint64 bijection (and exact inverse)
__device__ inline ull ordkey(double d) {
    long long b = __double_as_longlong(d);
    return (b < 0) ? ~(ull)b : ((ull)b | 0x8000000000000000ULL);
}
__device__ inline double keyord(ull u) {
    long long b = (u & 0x8000000000000000ULL)
                    ? (long long)(u & 0x7FFFFFFFFFFFFFFFULL)
                    : (long long)~u;
    return __longlong_as_double(b);
}
// total order: "a earlier than b" == key desc, node asc (== lax.top_k order)
__device__ inline bool gt(ull ka, int na, ull kb, int nb) {
    return (ka > kb) || (ka == kb && na < nb);
}

// in-wave bitonic sort of 64 (key,node) pairs, descending by gt. zero barriers.
__device__ inline void wsort64(ull& k, int& n, int lane) {
    for (int k2 = 2; k2 <= 64; k2 <<= 1) {
        for (int j = k2 >> 1; j; j >>= 1) {
            ull ok = __shfl_xor(k, j, 64);
            int on = __shfl_xor(n, j, 64);
            bool isLow = (lane & j) == 0;
            bool d = (k2 == 64) || ((lane & k2) == 0);
            bool wantMax = (d == isLow);
            if (wantMax == gt(ok, on, k, n)) { k = ok; n = on; }
        }
    }
}
// in-wave bitonic merge (input bitonic), descending by gt
__device__ inline void wmerge64(ull& k, int& n, int lane) {
    for (int j = 32; j; j >>= 1) {
        ull ok = __shfl_xor(k, j, 64);
        int on = __shfl_xor(n, j, 64);
        bool wantMax = (lane & j) == 0;
        if (wantMax == gt(ok, on, k, n)) { k = ok; n = on; }
    }
}
// fold a sorted-desc 64-run (k,n) into sorted-desc accumulator (ak,an): exact top-64
__device__ inline void wfold(ull& ak, int& an, ull k, int n, int lane) {
    ull rk = __shfl(k, 63 - lane, 64);
    int rn = __shfl(n, 63 - lane, 64);
    if (gt(rk, rn, ak, an)) { ak = rk; an = rn; }   // bitonic split
    wmerge64(ak, an, lane);
}

union SMem {
    struct {
        float inp[KK][DD + 1];
        int rowS[KK];
        double q[DD], lg[KK], sr[KK], pre[DD], red[DD];
    } m;                                          // mem step  (~37.4 KB) — union max
    struct {
        int pair[CHUNK * CC];                     // packed (ln<<12)|(rank<<4)|c, 12.3KB
        double hxnL[CC * 129];                    // padded hxn, 16.5KB
        int lcnt[CC], base[CC], npair;
    } cd;                                         // candidate (~29 KB)
    struct { int sn[CC * SS]; } sd;               // seeds
};

__global__ __launch_bounds__(256, 4)
void k_all(const float* __restrict__ es, const int* __restrict__ edge,
           const int* __restrict__ seeds, const float* __restrict__ Wm,
           float* __restrict__ out,
           double* __restrict__ inv_norm, int* __restrict__ known,
           unsigned* __restrict__ cate, unsigned* __restrict__ nbr,
           double* __restrict__ hx, double* __restrict__ hxn,
           int* __restrict__ last, int* __restrict__ cnt,
           ull* __restrict__ tkey, int* __restrict__ tnode,
           int* __restrict__ cidx, ull* __restrict__ ckey, int cap) {
    __shared__ SMem sm;
    int tid = threadIdx.x, wave = tid >> 6, lane = tid & 63;

    // ================= phase 0: norms + state init + seeding =================
    if (tid < CC * SS) sm.sd.sn[tid] = seeds[tid];
    __syncthreads();
    for (int n = blockIdx.x * 4 + wave; n < NN; n += GRID * 4) {
        float a = es[(long)n * DD + lane];
        float b = es[(long)n * DD + 64 + lane];
        double p = (double)a * (double)a + (double)b * (double)b;
        for (int o = 32; o > 0; o >>= 1) p += __shfl_xor(p, o, 64);
        unsigned bits = 0;
        #pragma unroll
        for (int j = 0; j < 4; ++j) {
            int idx = lane * 4 + j;
            if (sm.sd.sn[idx] == n) bits |= 1u << (idx >> 4);   // class = idx/SS
        }
        for (int o = 32; o > 0; o >>= 1) bits |= __shfl_xor(bits, o, 64);
        if (lane == 0) {
            inv_norm[n] = 1.0 / (sqrt(p) + 1e-8);
            known[n] = bits ? 0 : INF_STAMP;   // seeds: known since iter 0
            cate[n] = bits;
            nbr[n] = 0;
        }
    }
    gridbar();

    for (int t = 0; t < NIT; ++t) {
        // ============ phase A: memory step (blocks 0..15) || edge pass ============
        if (blockIdx.x < CC) {
            int c = blockIdx.x;
            if (tid == 0) cnt[c * CNT_STRIDE] = 0;
            int k = (t == 0) ? SS : KK;
            if (tid < KK) {
                sm.m.lg[tid] = -1.0e308;
                if (tid < k) sm.m.rowS[tid] = (t == 0) ? seeds[c * SS + tid]
                                                       : last[c * KK + tid];
            }
            __syncthreads();
            for (int i = tid; i < k * DD; i += 256)
                sm.m.inp[i >> 7][i & 127] = es[(long)sm.m.rowS[i >> 7] * DD + (i & 127)];
            __syncthreads();
            if (tid < DD) {
                if (t == 0) {
                    double s = 0;
                    for (int j = 0; j < k; ++j) s += (double)sm.m.inp[j][tid];
                    sm.m.q[tid] = s / (double)k;
                } else {
                    sm.m.q[tid] = hx[c * DD + tid];
                }
            }
            __syncthreads();
            if (tid < k) {
                double s = 0;
                for (int i = 0; i < DD; ++i) s += (double)sm.m.inp[tid][i] * sm.m.q[i];
                sm.m.lg[tid] = s / sqrt((double)DD);
            }
            __syncthreads();
            if (tid < KK) sm.m.sr[tid] = sm.m.lg[tid];
            __syncthreads();
            for (int st = 32; st > 0; st >>= 1) {
                if (tid < st) sm.m.sr[tid] = fmax(sm.m.sr[tid], sm.m.sr[tid + st]);
                __syncthreads();
            }
            double mx = sm.m.sr[0];
            __syncthreads();
            if (tid < KK) {
                double e = (tid < k) ? exp(sm.m.lg[tid] - mx) : 0.0;
                sm.m.lg[tid] = e; sm.m.sr[tid] = e;
            }
            __syncthreads();
            for (int st = 32; st > 0; st >>= 1) {
                if (tid < st) sm.m.sr[tid] += sm.m.sr[tid + st];
                __syncthreads();
            }
            double smm = sm.m.sr[0];
            __syncthreads();
            if (tid < KK) sm.m.lg[tid] /= smm;
            __syncthreads();
            if (tid < DD) {
                double ctx = 0;
                for (int j = 0; j < k; ++j) ctx += sm.m.lg[j] * (double)sm.m.inp[j][tid];
                sm.m.pre[tid] = (t == 0) ? ctx : (ctx + sm.m.q[tid]);
            }
            __syncthreads();
            double h = 0;
            if (tid < DD) {
                for (int i = 0; i < DD; ++i) h += sm.m.pre[i] * (double)Wm[i * DD + tid];
                h = tanh(h);
                sm.m.red[tid] = h * h;
            }
            __syncthreads();
            for (int st = 64; st > 0; st >>= 1) {
                if (tid < st) sm.m.red[tid] += sm.m.red[tid + st];
                __syncthreads();
            }
            if (tid < DD) {
                double inv = 1.0 / (sqrt(sm.m.red[0]) + 1e-8);
                hx[c * DD + tid] = h;
                hxn[c * DD + tid] = h * inv;
                out[2 * NIT * CC * KK + t * CC * DD + c * DD + tid] = (float)h;  // hxes
            }
        } else {
            const int stripe = (EE + (GRID - CC) - 1) / (GRID - CC);
            long e0 = (long)(blockIdx.x - CC) * stripe;
            long e1 = e0 + stripe; if (e1 > EE) e1 = EE;
            for (long e = e0 + tid; e < e1; e += 256) {
                int s = edge[e];
                unsigned mm = cate[s];
                if (mm) atomicOr(&nbr[edge[EE + e]], mm);
            }
        }
        gridbar();

        // ================ phase B: candidate scoring (521 chunks) ================
        for (int i = tid; i < CC * DD; i += 256)
            sm.cd.hxnL[(i >> 7) * 129 + (i & 127)] = hxn[i];
        __syncthreads();
        for (int vb = blockIdx.x; vb < NCH; vb += GRID) {
            if (tid < CC) sm.cd.lcnt[tid] = 0;
            if (tid == 0) sm.cd.npair = 0;
            __syncthreads();
            if (tid < CHUNK) {
                int n = vb * CHUNK + tid;
                unsigned m = 0;
                if (n < NN && known[n] > t) m = nbr[n];  // stamp>t <=> unknown at iter t
                while (m) {
                    int c = __ffs(m) - 1;
                    m &= m - 1;
                    int r = atomicAdd(&sm.cd.lcnt[c], 1);
                    int p = atomicAdd(&sm.cd.npair, 1);
                    sm.cd.pair[p] = (tid << 12) | (r << 4) | c;
                }
            }
            __syncthreads();
            if (tid < CC && sm.cd.lcnt[tid] > 0)
                sm.cd.base[tid] = atomicAdd(&cnt[tid * CNT_STRIDE], sm.cd.lcnt[tid]);
            __syncthreads();
            int np = sm.cd.npair;
            for (int t2 = tid; t2 < np; t2 += 256) {
                int pk = sm.cd.pair[t2];
                int c = pk & 15, r = (pk >> 4) & 255, ln = pk >> 12;
                int nn = vb * CHUNK + ln;
                const float4* row = (const float4*)(es + (long)nn * DD);
                const double* h = &sm.cd.hxnL[c * 129];
                double s = 0;
                #pragma unroll
                for (int i = 0; i < 32; ++i) {
                    float4 v = row[i];
                    s += (double)v.x * h[4 * i + 0] + (double)v.y * h[4 * i + 1]
                       + (double)v.z * h[4 * i + 2] + (double)v.w * h[4 * i + 3];
                }
                int pos = sm.cd.base[c] + r;
                if (pos < cap) {
                    cidx[(long)c * cap + pos] = nn;
                    ckey[(long)c * cap + pos] = ordkey(s * inv_norm[nn]);
                }
            }
            __syncthreads();
        }
        gridbar();

        // ==== phase C: 1024 wave-slices, register-streaming exact top-64 (no LDS) ====
        {
            int gw = blockIdx.x * 4 + wave;
            if (gw < CC * RUNS) {
                int c = gw >> 6, w = gw & 63;
                int count = min(cnt[c * CNT_STRIDE], cap);
                int per = (count + RUNS - 1) / RUNS;
                int lo = w * per;
                int hi = min(count, lo + per);
                ull ak = 0ULL; int an = 0x7FFFFFFF;     // acc = pads
                for (int base = lo; base < hi; base += 64) {
                    int idx = base + lane;
                    ull k; int n;
                    if (idx < hi) { k = ckey[(long)c * cap + idx];
                                    n = cidx[(long)c * cap + idx]; }
                    else          { k = 0ULL; n = 0x7FFFFFFF; }
                    wsort64(k, n, lane);
                    wfold(ak, an, k, n, lane);
                }
                tkey[((long)c * RUNS + w) * 64 + lane] = ak;
                tnode[((long)c * RUNS + w) * 64 + lane] = an;
            }
        }
        gridbar();

        // ==== phase D: one wave/class folds 64 runs -> top-64, updates + outputs ====
        if (blockIdx.x < CC && wave == 0) {
            int c = blockIdx.x;
            ull ak = 0ULL; int an = 0x7FFFFFFF;
            for (int r = 0; r < RUNS; ++r) {
                ull k = tkey[((long)c * RUNS + r) * 64 + lane];
                int n = tnode[((long)c * RUNS + r) * 64 + lane];
                wfold(ak, an, k, n, lane);
            }
            int count = min(cnt[c * CNT_STRIDE], cap);
            int nsel = min(count, KK);
            if (lane < nsel) {                 // lane i holds rank-i element
                int n = an;
                out[t * CC * KK + c * KK + lane] = (float)keyord(ak);       // outs
                out[NIT * CC * KK + t * CC * KK + c * KK + lane] = (float)n; // exps
                last[c * KK + lane] = n;
                known[n] = t + 1;              // stamp invisible to this iter's tests
                atomicOr(&cate[n], 1u << c);
            }
            // fill path: lowest-index invalid nodes, prob=-1e9. stamp test sees only
            // pre-iteration state -> race-free vs concurrent t+1 stamps (== reference).
            if (lane == 0 && nsel < KK) {
                int r = nsel;
                for (int n = 0; n < NN && r < KK; ++n) {
                    bool valid = ((nbr[n] >> c) & 1u) && (known[n] > t);
                    if (!valid) {
                        out[t * CC * KK + c * KK + r] = -1e9f;
                        out[NIT * CC * KK + t * CC * KK + c * KK + r] = (float)n;
                        last[c * KK + r] = n;
                        known[n] = t + 1;
                        atomicOr(&cate[n], 1u << c);
                        ++r;
                    }
                }
            }
        }
        gridbar();
    }
}

// -------------------- host launcher --------------------

extern "C" void kernel_launch(void* const* d_in, const int* in_sizes, int n_in,
                              void* d_out, int out_size, void* d_ws, size_t ws_size,
                              hipStream_t stream) {
    const float* es    = (const float*)d_in[0];
    const int*   edge  = (const int*)d_in[1];
    const int*   seeds = (const int*)d_in[2];
    const float* W     = (const float*)d_in[3];
    float* out = (float*)d_out;

    char* p = (char*)d_ws;
    auto alloc = [&](size_t bytes) -> char* {
        char* r = p;
        p += (bytes + 255) & ~(size_t)255;
        return r;
    };
    double*   inv_norm = (double*)alloc((size_t)NN * 8);
    int*      known    = (int*)alloc((size_t)NN * 4);
    unsigned* cate     = (unsigned*)alloc((size_t)NN * 4);
    unsigned* nbr      = (unsigned*)alloc((size_t)NN * 4);
    double*   hx       = (double*)alloc(CC * DD * 8);
    double*   hxn      = (double*)alloc(CC * DD * 8);
    int*      last     = (int*)alloc(CC * KK * 4);
    int*      cnt      = (int*)alloc(CC * CNT_STRIDE * 4);
    ull*      tkey     = (ull*)alloc((size_t)CC * RUNS * 64 * 8);
    int*      tnode    = (int*)alloc((size_t)CC * RUNS * 64 * 4);
    size_t used = (size_t)(p - (char*)d_ws);
    size_t rem = (ws_size > used + 8192) ? (ws_size - used - 8192) : 0;
    long capl = (long)(rem / (CC * 12));
    if (capl > NN) capl = NN;
    if (capl < 1) capl = 1;
    int cap = (int)capl;
    int*    cidx = (int*)alloc((size_t)CC * cap * 4);
    ull*    ckey = (ull*)alloc((size_t)CC * cap * 8);

    k_all<<<GRID, 256, 0, stream>>>(es, edge, seeds, W, out,
                                    inv_norm, known, cate, nbr, hx, hxn,
                                    last, cnt, tkey, tnode, cidx, ckey, cap);
}

// Round 8
// 479.320 us; speedup vs baseline: 13.7584x; 13.7584x over previous
//
#include <hip/hip_runtime.h>
#include <math.h>

#define NN 100000
#define DD 128
#define CC 16
#define SS 16
#define EE 3200000
#define KK 64
#define NIT 4
#define CNT_STRIDE 32      // pad per-class counters 128B apart
#define RUNS 64            // stage-A wave-slices per class
#define CHUNK 256          // nodes per candidate chunk
#define NCH ((NN + CHUNK - 1) / CHUNK)   // 391
#define EB ((EE + 255) / 256)
#define INF_STAMP 0x7fffffff

typedef unsigned long long ull;

// order-preserving double -> uint64 bijection (and exact inverse)
__device__ inline ull ordkey(double d) {
    long long b = __double_as_longlong(d);
    return (b < 0) ? ~(ull)b : ((ull)b | 0x8000000000000000ULL);
}
__device__ inline double keyord(ull u) {
    long long b = (u & 0x8000000000000000ULL)
                    ? (long long)(u & 0x7FFFFFFFFFFFFFFFULL)
                    : (long long)~u;
    return __longlong_as_double(b);
}
// total order: "a earlier than b" == key desc, node asc (== lax.top_k order)
__device__ inline bool gt(ull ka, int na, ull kb, int nb) {
    return (ka > kb) || (ka == kb && na < nb);
}

// in-wave bitonic sort of 64 (key,node) pairs, descending by gt. zero barriers.
__device__ inline void wsort64(ull& k, int& n, int lane) {
    for (int k2 = 2; k2 <= 64; k2 <<= 1) {
        for (int j = k2 >> 1; j; j >>= 1) {
            ull ok = __shfl_xor(k, j, 64);
            int on = __shfl_xor(n, j, 64);
            bool isLow = (lane & j) == 0;
            bool d = (k2 == 64) || ((lane & k2) == 0);
            bool wantMax = (d == isLow);
            if (wantMax == gt(ok, on, k, n)) { k = ok; n = on; }
        }
    }
}
// in-wave bitonic merge (input bitonic), descending by gt
__device__ inline void wmerge64(ull& k, int& n, int lane) {
    for (int j = 32; j; j >>= 1) {
        ull ok = __shfl_xor(k, j, 64);
        int on = __shfl_xor(n, j, 64);
        bool wantMax = (lane & j) == 0;
        if (wantMax == gt(ok, on, k, n)) { k = ok; n = on; }
    }
}
// fold a sorted-desc 64-run (k,n) into sorted-desc accumulator (ak,an): exact top-64
__device__ inline void wfold(ull& ak, int& an, ull k, int n, int lane) {
    ull rk = __shfl(k, 63 - lane, 64);
    int rn = __shfl(n, 63 - lane, 64);
    if (gt(rk, rn, ak, an)) { ak = rk; an = rn; }   // bitonic split
    wmerge64(ak, an, lane);
}

// -------------------- init: norms + state reset + seeding (fused) --------------------

__global__ __launch_bounds__(256)
void k_init(const float* __restrict__ es, const int* __restrict__ seeds,
            double* __restrict__ inv_norm, int* __restrict__ known,
            unsigned* __restrict__ cate, unsigned* __restrict__ nbr) {
    __shared__ int sn[CC * SS];
    int tid = threadIdx.x, wave = tid >> 6, lane = tid & 63;
    if (tid < CC * SS) sn[tid] = seeds[tid];
    __syncthreads();
    int n = blockIdx.x * 4 + wave;
    if (n >= NN) return;
    float a = es[(long)n * DD + lane];
    float b = es[(long)n * DD + 64 + lane];
    double p = (double)a * (double)a + (double)b * (double)b;
    for (int o = 32; o > 0; o >>= 1) p += __shfl_xor(p, o, 64);
    unsigned bits = 0;
    #pragma unroll
    for (int j = 0; j < 4; ++j) {
        int idx = lane * 4 + j;
        if (sn[idx] == n) bits |= 1u << (idx >> 4);   // class = idx/SS
    }
    for (int o = 32; o > 0; o >>= 1) bits |= __shfl_xor(bits, o, 64);
    if (lane == 0) {
        inv_norm[n] = 1.0 / (sqrt(p) + 1e-8);
        known[n] = bits ? 0 : INF_STAMP;   // seeds: known since iteration 0
        cate[n] = bits;
        nbr[n] = 0;
    }
}

// ------------- fused: memory step (blocks 0..15) + edge pass (rest) -------------

__global__ __launch_bounds__(256)
void k_memedge(const float* __restrict__ es, const float* __restrict__ Wm,
               const int* __restrict__ seeds, const int* __restrict__ last,
               double* __restrict__ hx, double* __restrict__ hxn,
               float* __restrict__ out, int* __restrict__ cnt, int* __restrict__ done,
               const int* __restrict__ edge, const unsigned* __restrict__ cate,
               unsigned* __restrict__ nbr, int t) {
    __shared__ float  inp[KK][DD + 1];
    __shared__ int    rowS[KK];
    __shared__ double q[DD], lg[KK], sr[KK], pre[DD], red[DD];
    int tid = threadIdx.x;

    if (blockIdx.x >= CC) {
        long e = (long)(blockIdx.x - CC) * 256 + tid;
        if (e < EE) {
            int s = edge[e];
            unsigned m = cate[s];
            if (m) atomicOr(&nbr[edge[EE + e]], m);
        }
        return;
    }

    int c = blockIdx.x;
    if (tid == 0) { cnt[c * CNT_STRIDE] = 0; done[c * CNT_STRIDE] = 0; }
    int k = (t == 0) ? SS : KK;
    if (tid < KK) {
        lg[tid] = -1.0e308;
        if (tid < k) rowS[tid] = (t == 0) ? seeds[c * SS + tid] : last[c * KK + tid];
    }
    __syncthreads();
    for (int i = tid; i < k * DD; i += 256)
        inp[i >> 7][i & 127] = es[(long)rowS[i >> 7] * DD + (i & 127)];
    __syncthreads();
    if (tid < DD) {
        if (t == 0) {
            double s = 0;
            for (int j = 0; j < k; ++j) s += (double)inp[j][tid];
            q[tid] = s / (double)k;
        } else {
            q[tid] = hx[c * DD + tid];
        }
    }
    __syncthreads();
    if (tid < k) {
        double s = 0;
        for (int i = 0; i < DD; ++i) s += (double)inp[tid][i] * q[i];
        lg[tid] = s / sqrt((double)DD);
    }
    __syncthreads();
    if (tid < KK) sr[tid] = lg[tid];
    __syncthreads();
    for (int st = 32; st > 0; st >>= 1) {
        if (tid < st) sr[tid] = fmax(sr[tid], sr[tid + st]);
        __syncthreads();
    }
    double mx = sr[0];
    __syncthreads();
    if (tid < KK) {
        double e = (tid < k) ? exp(lg[tid] - mx) : 0.0;
        lg[tid] = e; sr[tid] = e;
    }
    __syncthreads();
    for (int st = 32; st > 0; st >>= 1) {
        if (tid < st) sr[tid] += sr[tid + st];
        __syncthreads();
    }
    double sm = sr[0];
    __syncthreads();
    if (tid < KK) lg[tid] /= sm;
    __syncthreads();
    if (tid < DD) {
        double ctx = 0;
        for (int j = 0; j < k; ++j) ctx += lg[j] * (double)inp[j][tid];
        pre[tid] = (t == 0) ? ctx : (ctx + q[tid]);
    }
    __syncthreads();
    double h = 0;
    if (tid < DD) {
        for (int i = 0; i < DD; ++i) h += pre[i] * (double)Wm[i * DD + tid];
        h = tanh(h);
        red[tid] = h * h;
    }
    __syncthreads();
    for (int st = 64; st > 0; st >>= 1) {
        if (tid < st) red[tid] += red[tid + st];
        __syncthreads();
    }
    if (tid < DD) {
        double inv = 1.0 / (sqrt(red[0]) + 1e-8);
        hx[c * DD + tid] = h;
        hxn[c * DD + tid] = h * inv;
        out[2 * NIT * CC * KK + t * CC * DD + c * DD + tid] = (float)h;  // hxes
    }
}

// -------------------- candidate scoring: block-aggregated, thread-per-pair --------------------

__global__ __launch_bounds__(256)
void k_cand(const float* __restrict__ es, const double* __restrict__ inv_norm,
            const int* __restrict__ known, const unsigned* __restrict__ nbr,
            const double* __restrict__ hxn,
            int* __restrict__ cnt, int* __restrict__ cidx,
            ull* __restrict__ ckey, int cap, int t) {
    __shared__ int    pair[CHUNK * CC];   // packed (ln<<12)|(rank<<4)|c, 16KB
    __shared__ double hxnL[CC * 129];     // padded hxn, 16.5KB
    __shared__ int    lcnt[CC], base[CC], npair;
    int tid = threadIdx.x;

    for (int i = tid; i < CC * DD; i += 256)
        hxnL[(i >> 7) * 129 + (i & 127)] = hxn[i];
    if (tid < CC) lcnt[tid] = 0;
    if (tid == 0) npair = 0;
    __syncthreads();

    int n = blockIdx.x * CHUNK + tid;
    unsigned m = 0;
    if (n < NN && known[n] > t) m = nbr[n];   // stamp > t  <=>  unknown at iter t
    while (m) {
        int c = __ffs(m) - 1;
        m &= m - 1;
        int r = atomicAdd(&lcnt[c], 1);
        int p = atomicAdd(&npair, 1);
        pair[p] = (tid << 12) | (r << 4) | c;
    }
    __syncthreads();

    if (tid < CC && lcnt[tid] > 0)
        base[tid] = atomicAdd(&cnt[tid * CNT_STRIDE], lcnt[tid]);
    __syncthreads();

    int np = npair;
    for (int t2 = tid; t2 < np; t2 += 256) {
        int pk = pair[t2];
        int c = pk & 15, r = (pk >> 4) & 255, ln = pk >> 12;
        int nn = blockIdx.x * CHUNK + ln;
        const float4* row = (const float4*)(es + (long)nn * DD);
        const double* h = &hxnL[c * 129];
        double s = 0;
        #pragma unroll
        for (int i = 0; i < 32; ++i) {
            float4 v = row[i];
            s += (double)v.x * h[4 * i + 0] + (double)v.y * h[4 * i + 1]
               + (double)v.z * h[4 * i + 2] + (double)v.w * h[4 * i + 3];
        }
        int pos = base[c] + r;
        if (pos < cap) {
            cidx[(long)c * cap + pos] = nn;
            ckey[(long)c * cap + pos] = ordkey(s * inv_norm[nn]);
        }
    }
}

// ---- fused top-K: 256 blocks register-stream slices; last block per class folds ----
// ---- 64 runs -> exact top-64, applies updates + outputs (completion counter) ----

__global__ __launch_bounds__(256)
void k_topmerge(const int* __restrict__ cnt, const int* __restrict__ cidx,
                const ull* __restrict__ ckey, int* __restrict__ done,
                ull* __restrict__ tkey, int* __restrict__ tnode,
                int* __restrict__ known, const unsigned* __restrict__ nbr,
                unsigned* __restrict__ cate, int* __restrict__ last,
                float* __restrict__ out, int cap, int t) {
    __shared__ int win;
    int tid = threadIdx.x, wave = tid >> 6, lane = tid & 63;
    int c = blockIdx.x >> 4;            // 16 blocks per class
    int w = (blockIdx.x & 15) * 4 + wave;   // wave-slice id in [0,64)
    int count = min(cnt[c * CNT_STRIDE], cap);
    int per = (count + RUNS - 1) / RUNS;
    int lo = w * per, hi = min(count, lo + per);
    ull ak = 0ULL; int an = 0x7FFFFFFF;     // accumulator = pads
    for (int bs = lo; bs < hi; bs += 64) {
        int idx = bs + lane;
        ull k; int n;
        if (idx < hi) { k = ckey[(long)c * cap + idx]; n = cidx[(long)c * cap + idx]; }
        else          { k = 0ULL; n = 0x7FFFFFFF; }
        wsort64(k, n, lane);
        wfold(ak, an, k, n, lane);
    }
    tkey[((long)c * RUNS + w) * 64 + lane] = ak;
    tnode[((long)c * RUNS + w) * 64 + lane] = an;
    __syncthreads();                    // drains vmcnt (stores complete)
    if (tid == 0) {
        // one-shot release-acquire completion counter (no spinning)
        int prev = __hip_atomic_fetch_add(&done[c * CNT_STRIDE], 1,
                                          __ATOMIC_ACQ_REL, __HIP_MEMORY_SCOPE_AGENT);
        win = (prev == 15);
    }
    __syncthreads();
    if (!win) return;

    // -------- winner block: fold 64 sorted runs -> exact top-64, update --------
    if (wave == 0) {
        ull fk = 0ULL; int fn = 0x7FFFFFFF;
        for (int r = 0; r < RUNS; ++r) {
            ull k = tkey[((long)c * RUNS + r) * 64 + lane];
            int n = tnode[((long)c * RUNS + r) * 64 + lane];
            wfold(fk, fn, k, n, lane);
        }
        int nsel = min(count, KK);
        if (lane < nsel) {              // lane i holds rank-i element
            int n = fn;
            out[t * CC * KK + c * KK + lane] = (float)keyord(fk);        // outs
            out[NIT * CC * KK + t * CC * KK + c * KK + lane] = (float)n; // exps
            last[c * KK + lane] = n;
            known[n] = t + 1;           // stamp invisible to this iteration's tests
            atomicOr(&cate[n], 1u << c);
        }
        // fill path: lowest-index invalid nodes, prob=-1e9. stamp test sees only
        // pre-iteration state -> race-free vs concurrent t+1 stamps (== reference).
        if (lane == 0 && nsel < KK) {
            int r = nsel;
            for (int n = 0; n < NN && r < KK; ++n) {
                bool valid = ((nbr[n] >> c) & 1u) && (known[n] > t);
                if (!valid) {
                    out[t * CC * KK + c * KK + r] = -1e9f;
                    out[NIT * CC * KK + t * CC * KK + c * KK + r] = (float)n;
                    last[c * KK + r] = n;
                    known[n] = t + 1;
                    atomicOr(&cate[n], 1u << c);
                    ++r;
                }
            }
        }
    }
}

// -------------------- host launcher --------------------

extern "C" void kernel_launch(void* const* d_in, const int* in_sizes, int n_in,
                              void* d_out, int out_size, void* d_ws, size_t ws_size,
                              hipStream_t stream) {
    const float* es    = (const float*)d_in[0];
    const int*   edge  = (const int*)d_in[1];
    const int*   seeds = (const int*)d_in[2];
    const float* W     = (const float*)d_in[3];
    float* out = (float*)d_out;

    char* p = (char*)d_ws;
    auto alloc = [&](size_t bytes) -> char* {
        char* r = p;
        p += (bytes + 255) & ~(size_t)255;
        return r;
    };
    double*   inv_norm = (double*)alloc((size_t)NN * 8);
    int*      known    = (int*)alloc((size_t)NN * 4);
    unsigned* cate     = (unsigned*)alloc((size_t)NN * 4);
    unsigned* nbr      = (unsigned*)alloc((size_t)NN * 4);
    double*   hx       = (double*)alloc(CC * DD * 8);
    double*   hxn      = (double*)alloc(CC * DD * 8);
    int*      last     = (int*)alloc(CC * KK * 4);
    int*      cnt      = (int*)alloc(CC * CNT_STRIDE * 4);
    int*      done     = (int*)alloc(CC * CNT_STRIDE * 4);
    ull*      tkey     = (ull*)alloc((size_t)CC * RUNS * 64 * 8);
    int*      tnode    = (int*)alloc((size_t)CC * RUNS * 64 * 4);
    size_t used = (size_t)(p - (char*)d_ws);
    size_t rem = (ws_size > used + 8192) ? (ws_size - used - 8192) : 0;
    long capl = (long)(rem / (CC * 12));
    if (capl > NN) capl = NN;
    if (capl < 1) capl = 1;
    int cap = (int)capl;
    int*    cidx = (int*)alloc((size_t)CC * cap * 4);
    ull*    ckey = (ull*)alloc((size_t)CC * cap * 8);

    k_init<<<(NN + 3) / 4, 256, 0, stream>>>(es, seeds, inv_norm, known, cate, nbr);

    for (int t = 0; t < NIT; ++t) {
        k_memedge<<<CC + EB, 256, 0, stream>>>(es, W, seeds, last, hx, hxn, out,
                                               cnt, done, edge, cate, nbr, t);
        k_cand<<<NCH, 256, 0, stream>>>(es, inv_norm, known, nbr, hxn,
                                        cnt, cidx, ckey, cap, t);
        k_topmerge<<<CC * 16, 256, 0, stream>>>(cnt, cidx, ckey, done, tkey, tnode,
                                                known, nbr, cate, last, out, cap, t);
    }
}

// Round 9
// 462.947 us; speedup vs baseline: 14.2450x; 1.0354x over previous
//
#include <hip/hip_runtime.h>
#include <math.h>

#define NN 100000
#define DD 128
#define CC 16
#define SS 16
#define EE 3200000
#define KK 64
#define NIT 4
#define CNT_STRIDE 32      // pad per-class counters 128B apart
#define NB 32              // stage-A blocks per class
#define SLMAX 4096         // max slice (pow2 >= ceil(NN/NB)=3125)
#define MM (NB * KK)       // merge size = 2048
#define CHUNK 256          // nodes per candidate chunk
#define NCH ((NN + CHUNK - 1) / CHUNK)   // 391
#define EB ((EE + 255) / 256)
#define INF_STAMP 0x7fffffff

typedef unsigned long long ull;

// order-preserving double -> uint64 bijection (and exact inverse)
__device__ inline ull ordkey(double d) {
    long long b = __double_as_longlong(d);
    return (b < 0) ? ~(ull)b : ((ull)b | 0x8000000000000000ULL);
}
__device__ inline double keyord(ull u) {
    long long b = (u & 0x8000000000000000ULL)
                    ? (long long)(u & 0x7FFFFFFFFFFFFFFFULL)
                    : (long long)~u;
    return __longlong_as_double(b);
}
// total order: "a earlier than b" == key desc, node asc (== lax.top_k order)
__device__ inline bool gt(ull ka, int na, ull kb, int nb) {
    return (ka > kb) || (ka == kb && na < nb);
}

// in-wave bitonic sort of 64 (key,node) pairs, descending by gt. zero barriers.
__device__ inline void wsort64(ull& k, int& n, int lane) {
    for (int k2 = 2; k2 <= 64; k2 <<= 1) {
        for (int j = k2 >> 1; j; j >>= 1) {
            ull ok = __shfl_xor(k, j, 64);
            int on = __shfl_xor(n, j, 64);
            bool isLow = (lane & j) == 0;
            bool d = (k2 == 64) || ((lane & k2) == 0);
            bool wantMax = (d == isLow);
            if (wantMax == gt(ok, on, k, n)) { k = ok; n = on; }
        }
    }
}
// in-wave bitonic merge (input bitonic), descending by gt
__device__ inline void wmerge64(ull& k, int& n, int lane) {
    for (int j = 32; j; j >>= 1) {
        ull ok = __shfl_xor(k, j, 64);
        int on = __shfl_xor(n, j, 64);
        bool wantMax = (lane & j) == 0;
        if (wantMax == gt(ok, on, k, n)) { k = ok; n = on; }
    }
}

// -------------------- init: norms + state reset + seeding (fused) --------------------

__global__ __launch_bounds__(256)
void k_init(const float* __restrict__ es, const int* __restrict__ seeds,
            double* __restrict__ inv_norm, int* __restrict__ known,
            unsigned* __restrict__ cate, unsigned* __restrict__ nbr) {
    __shared__ int sn[CC * SS];
    int tid = threadIdx.x, wave = tid >> 6, lane = tid & 63;
    if (tid < CC * SS) sn[tid] = seeds[tid];
    __syncthreads();
    int n = blockIdx.x * 4 + wave;
    if (n >= NN) return;
    float a = es[(long)n * DD + lane];
    float b = es[(long)n * DD + 64 + lane];
    double p = (double)a * (double)a + (double)b * (double)b;
    for (int o = 32; o > 0; o >>= 1) p += __shfl_xor(p, o, 64);
    unsigned bits = 0;
    #pragma unroll
    for (int j = 0; j < 4; ++j) {
        int idx = lane * 4 + j;
        if (sn[idx] == n) bits |= 1u << (idx >> 4);   // class = idx/SS
    }
    for (int o = 32; o > 0; o >>= 1) bits |= __shfl_xor(bits, o, 64);
    if (lane == 0) {
        inv_norm[n] = 1.0 / (sqrt(p) + 1e-8);
        known[n] = bits ? 0 : INF_STAMP;   // seeds: known since iteration 0
        cate[n] = bits;
        nbr[n] = 0;
    }
}

// ------------- fused: memory step (blocks 0..15) + edge pass (rest) -------------

__global__ __launch_bounds__(256)
void k_memedge(const float* __restrict__ es, const float* __restrict__ Wm,
               const int* __restrict__ seeds, const int* __restrict__ last,
               double* __restrict__ hx, double* __restrict__ hxn,
               float* __restrict__ out, int* __restrict__ cnt, int* __restrict__ done,
               const int* __restrict__ edge, const unsigned* __restrict__ cate,
               unsigned* __restrict__ nbr, int t) {
    __shared__ float  inp[KK][DD + 1];
    __shared__ int    rowS[KK];
    __shared__ double q[DD], lg[KK], sr[KK], pre[DD], red[DD];
    int tid = threadIdx.x;

    if (blockIdx.x >= CC) {
        long e = (long)(blockIdx.x - CC) * 256 + tid;
        if (e < EE) {
            int s = edge[e];
            unsigned m = cate[s];
            if (m) atomicOr(&nbr[edge[EE + e]], m);
        }
        return;
    }

    int c = blockIdx.x;
    if (tid == 0) { cnt[c * CNT_STRIDE] = 0; done[c * CNT_STRIDE] = 0; }
    int k = (t == 0) ? SS : KK;
    if (tid < KK) {
        lg[tid] = -1.0e308;
        if (tid < k) rowS[tid] = (t == 0) ? seeds[c * SS + tid] : last[c * KK + tid];
    }
    __syncthreads();
    for (int i = tid; i < k * DD; i += 256)
        inp[i >> 7][i & 127] = es[(long)rowS[i >> 7] * DD + (i & 127)];
    __syncthreads();
    if (tid < DD) {
        if (t == 0) {
            double s = 0;
            for (int j = 0; j < k; ++j) s += (double)inp[j][tid];
            q[tid] = s / (double)k;
        } else {
            q[tid] = hx[c * DD + tid];
        }
    }
    __syncthreads();
    if (tid < k) {
        double s = 0;
        for (int i = 0; i < DD; ++i) s += (double)inp[tid][i] * q[i];
        lg[tid] = s / sqrt((double)DD);
    }
    __syncthreads();
    if (tid < KK) sr[tid] = lg[tid];
    __syncthreads();
    for (int st = 32; st > 0; st >>= 1) {
        if (tid < st) sr[tid] = fmax(sr[tid], sr[tid + st]);
        __syncthreads();
    }
    double mx = sr[0];
    __syncthreads();
    if (tid < KK) {
        double e = (tid < k) ? exp(lg[tid] - mx) : 0.0;
        lg[tid] = e; sr[tid] = e;
    }
    __syncthreads();
    for (int st = 32; st > 0; st >>= 1) {
        if (tid < st) sr[tid] += sr[tid + st];
        __syncthreads();
    }
    double sm = sr[0];
    __syncthreads();
    if (tid < KK) lg[tid] /= sm;
    __syncthreads();
    if (tid < DD) {
        double ctx = 0;
        for (int j = 0; j < k; ++j) ctx += lg[j] * (double)inp[j][tid];
        pre[tid] = (t == 0) ? ctx : (ctx + q[tid]);
    }
    __syncthreads();
    double h = 0;
    if (tid < DD) {
        for (int i = 0; i < DD; ++i) h += pre[i] * (double)Wm[i * DD + tid];
        h = tanh(h);
        red[tid] = h * h;
    }
    __syncthreads();
    for (int st = 64; st > 0; st >>= 1) {
        if (tid < st) red[tid] += red[tid + st];
        __syncthreads();
    }
    if (tid < DD) {
        double inv = 1.0 / (sqrt(red[0]) + 1e-8);
        hx[c * DD + tid] = h;
        hxn[c * DD + tid] = h * inv;
        out[2 * NIT * CC * KK + t * CC * DD + c * DD + tid] = (float)h;  // hxes
    }
}

// -------------------- candidate scoring: block-aggregated, thread-per-pair --------------------

__global__ __launch_bounds__(256)
void k_cand(const float* __restrict__ es, const double* __restrict__ inv_norm,
            const int* __restrict__ known, const unsigned* __restrict__ nbr,
            const double* __restrict__ hxn,
            int* __restrict__ cnt, int* __restrict__ cidx,
            ull* __restrict__ ckey, int cap, int t) {
    __shared__ int    pair[CHUNK * CC];   // packed (ln<<12)|(rank<<4)|c, 16KB
    __shared__ double hxnL[CC * 129];     // padded hxn, 16.5KB
    __shared__ int    lcnt[CC], base[CC], npair;
    int tid = threadIdx.x;

    for (int i = tid; i < CC * DD; i += 256)
        hxnL[(i >> 7) * 129 + (i & 127)] = hxn[i];
    if (tid < CC) lcnt[tid] = 0;
    if (tid == 0) npair = 0;
    __syncthreads();

    int n = blockIdx.x * CHUNK + tid;
    unsigned m = 0;
    if (n < NN && known[n] > t) m = nbr[n];   // stamp > t  <=>  unknown at iter t
    while (m) {
        int c = __ffs(m) - 1;
        m &= m - 1;
        int r = atomicAdd(&lcnt[c], 1);
        int p = atomicAdd(&npair, 1);
        pair[p] = (tid << 12) | (r << 4) | c;
    }
    __syncthreads();

    if (tid < CC && lcnt[tid] > 0)
        base[tid] = atomicAdd(&cnt[tid * CNT_STRIDE], lcnt[tid]);
    __syncthreads();

    int np = npair;
    for (int t2 = tid; t2 < np; t2 += 256) {
        int pk = pair[t2];
        int c = pk & 15, r = (pk >> 4) & 255, ln = pk >> 12;
        int nn = blockIdx.x * CHUNK + ln;
        const float4* row = (const float4*)(es + (long)nn * DD);
        const double* h = &hxnL[c * 129];
        double s = 0;
        #pragma unroll
        for (int i = 0; i < 32; ++i) {
            float4 v = row[i];
            s += (double)v.x * h[4 * i + 0] + (double)v.y * h[4 * i + 1]
               + (double)v.z * h[4 * i + 2] + (double)v.w * h[4 * i + 3];
        }
        int pos = base[c] + r;
        if (pos < cap) {
            cidx[(long)c * cap + pos] = nn;
            ckey[(long)c * cap + pos] = ordkey(s * inv_norm[nn]);
        }
    }
}

// ---- stage A+B fused: 32 blocks/class slice-sort top-64 (in-wave sorts + LDS tree);
// ---- last-arriving block per class merges 32 runs, applies updates + outputs ----

__global__ __launch_bounds__(256)
void k_top(const int* __restrict__ cnt, const int* __restrict__ cidx,
           const ull* __restrict__ ckey, int* __restrict__ done,
           ull* __restrict__ tkey, int* __restrict__ tnode,
           int* __restrict__ known, const unsigned* __restrict__ nbr,
           unsigned* __restrict__ cate, int* __restrict__ last,
           float* __restrict__ out, int cap, int t) {
    __shared__ ull ks[SLMAX];
    __shared__ int ns[SLMAX];
    __shared__ int win;
    int c = blockIdx.x / NB, b = blockIdx.x % NB;
    int tid = threadIdx.x, wave = tid >> 6, lane = tid & 63;
    int count = min(cnt[c * CNT_STRIDE], cap);
    int per = (count + NB - 1) / NB;
    int start = b * per;
    int m2 = min(per, count - start);
    int sl = 64;
    while (sl < per) sl <<= 1;
    int nruns = sl >> 6;
    // sort each 64-run inside one wave (registers, no barriers)
    for (int r = wave; r < nruns; r += 4) {
        int i = (r << 6) + lane;
        ull k; int n;
        if (i < m2) { k = ckey[(long)c * cap + start + i];
                      n = cidx[(long)c * cap + start + i]; }
        else        { k = 0ULL; n = 0x7FFFFFFF; }
        wsort64(k, n, lane);
        ks[i] = k; ns[i] = n;
    }
    __syncthreads();
    // merge tree: each pair handled by one wave; winner written over run A
    for (int step = 1; step < nruns; step <<= 1) {
        int npair2 = nruns / (2 * step);
        for (int pr = wave; pr < npair2; pr += 4) {
            int ra = pr * 2 * step, rb = ra + step;
            ull ka = ks[(ra << 6) + lane];       int na = ns[(ra << 6) + lane];
            ull kb = ks[(rb << 6) + 63 - lane];  int nb2 = ns[(rb << 6) + 63 - lane];
            if (gt(kb, nb2, ka, na)) { ka = kb; na = nb2; }   // bitonic split
            wmerge64(ka, na, lane);
            ks[(ra << 6) + lane] = ka; ns[(ra << 6) + lane] = na;
        }
        __syncthreads();
    }
    if (tid < KK) {
        tkey[(long)c * MM + b * KK + tid] = ks[tid];
        tnode[(long)c * MM + b * KK + tid] = ns[tid];
    }
    __threadfence();                      // device-scope: publish run before arrival
    __syncthreads();
    if (tid == 0) {
        int prev = __hip_atomic_fetch_add(&done[c * CNT_STRIDE], 1,
                                          __ATOMIC_ACQ_REL, __HIP_MEMORY_SCOPE_AGENT);
        win = (prev == NB - 1);
    }
    __syncthreads();
    if (!win) return;

    // ---- winner block (last arrival): block-wide stage of 32 runs + tree merge ----
    for (int i = tid; i < MM; i += 256) {
        ks[i] = tkey[(long)c * MM + i];
        ns[i] = tnode[(long)c * MM + i];
    }
    __syncthreads();
    for (int step = 1; step < NB; step <<= 1) {
        int npair2 = NB / (2 * step);
        for (int pr = wave; pr < npair2; pr += 4) {
            int ra = pr * 2 * step, rb = ra + step;
            ull ka = ks[(ra << 6) + lane];       int na = ns[(ra << 6) + lane];
            ull kb = ks[(rb << 6) + 63 - lane];  int nb2 = ns[(rb << 6) + 63 - lane];
            if (gt(kb, nb2, ka, na)) { ka = kb; na = nb2; }
            wmerge64(ka, na, lane);
            ks[(ra << 6) + lane] = ka; ns[(ra << 6) + lane] = na;
        }
        __syncthreads();
    }
    int nsel = min(count, KK);
    if (tid < KK && tid < nsel) {
        int n = ns[tid];
        out[t * CC * KK + c * KK + tid] = (float)keyord(ks[tid]);        // outs
        out[NIT * CC * KK + t * CC * KK + c * KK + tid] = (float)n;      // exps
        last[c * KK + tid] = n;
        known[n] = t + 1;                 // stamp invisible to this iteration's tests
        atomicOr(&cate[n], 1u << c);
    }
    // fill path: lowest-index invalid nodes, prob=-1e9. stamp test sees only
    // pre-iteration state -> race-free vs concurrent t+1 stamps (== reference).
    if (tid == 0 && nsel < KK) {
        int r = nsel;
        for (int n = 0; n < NN && r < KK; ++n) {
            bool valid = ((nbr[n] >> c) & 1u) && (known[n] > t);
            if (!valid) {
                out[t * CC * KK + c * KK + r] = -1e9f;
                out[NIT * CC * KK + t * CC * KK + c * KK + r] = (float)n;
                last[c * KK + r] = n;
                known[n] = t + 1;
                atomicOr(&cate[n], 1u << c);
                ++r;
            }
        }
    }
}

// -------------------- host launcher --------------------

extern "C" void kernel_launch(void* const* d_in, const int* in_sizes, int n_in,
                              void* d_out, int out_size, void* d_ws, size_t ws_size,
                              hipStream_t stream) {
    const float* es    = (const float*)d_in[0];
    const int*   edge  = (const int*)d_in[1];
    const int*   seeds = (const int*)d_in[2];
    const float* W     = (const float*)d_in[3];
    float* out = (float*)d_out;

    char* p = (char*)d_ws;
    auto alloc = [&](size_t bytes) -> char* {
        char* r = p;
        p += (bytes + 255) & ~(size_t)255;
        return r;
    };
    double*   inv_norm = (double*)alloc((size_t)NN * 8);
    int*      known    = (int*)alloc((size_t)NN * 4);
    unsigned* cate     = (unsigned*)alloc((size_t)NN * 4);
    unsigned* nbr      = (unsigned*)alloc((size_t)NN * 4);
    double*   hx       = (double*)alloc(CC * DD * 8);
    double*   hxn      = (double*)alloc(CC * DD * 8);
    int*      last     = (int*)alloc(CC * KK * 4);
    int*      cnt      = (int*)alloc(CC * CNT_STRIDE * 4);
    int*      done     = (int*)alloc(CC * CNT_STRIDE * 4);
    ull*      tkey     = (ull*)alloc((size_t)CC * MM * 8);
    int*      tnode    = (int*)alloc((size_t)CC * MM * 4);
    size_t used = (size_t)(p - (char*)d_ws);
    size_t rem = (ws_size > used + 8192) ? (ws_size - used - 8192) : 0;
    long capl = (long)(rem / (CC * 12));
    if (capl > NN) capl = NN;
    if (capl < 1) capl = 1;
    int cap = (int)capl;
    int*    cidx = (int*)alloc((size_t)CC * cap * 4);
    ull*    ckey = (ull*)alloc((size_t)CC * cap * 8);

    k_init<<<(NN + 3) / 4, 256, 0, stream>>>(es, seeds, inv_norm, known, cate, nbr);

    for (int t = 0; t < NIT; ++t) {
        k_memedge<<<CC + EB, 256, 0, stream>>>(es, W, seeds, last, hx, hxn, out,
                                               cnt, done, edge, cate, nbr, t);
        k_cand<<<NCH, 256, 0, stream>>>(es, inv_norm, known, nbr, hxn,
                                        cnt, cidx, ckey, cap, t);
        k_top<<<CC * NB, 256, 0, stream>>>(cnt, cidx, ckey, done, tkey, tnode,
                                           known, nbr, cate, last, out, cap, t);
    }
}

// Round 10
// 313.556 us; speedup vs baseline: 21.0319x; 1.4764x over previous
//
#include <hip/hip_runtime.h>
#include <math.h>

#define NN 100000
#define DD 128
#define CC 16
#define SS 16
#define EE 3200000
#define KK 64
#define NIT 4
#define CNT_STRIDE 32      // pad per-class counters 128B apart
#define NB 32              // stage-A blocks per class
#define SLMAX 4096         // max slice (pow2 >= ceil(NN/NB)=3125)
#define MM (NB * KK)       // merge size = 2048
#define CHUNK 256          // nodes per candidate chunk
#define NCH ((NN + CHUNK - 1) / CHUNK)   // 391
#define EB ((EE + 255) / 256)
#define INF_STAMP 0x7fffffff

typedef unsigned long long ull;

// order-preserving double -> uint64 bijection (and exact inverse)
__device__ inline ull ordkey(double d) {
    long long b = __double_as_longlong(d);
    return (b < 0) ? ~(ull)b : ((ull)b | 0x8000000000000000ULL);
}
__device__ inline double keyord(ull u) {
    long long b = (u & 0x8000000000000000ULL)
                    ? (long long)(u & 0x7FFFFFFFFFFFFFFFULL)
                    : (long long)~u;
    return __longlong_as_double(b);
}
// total order: "a earlier than b" == key desc, node asc (== lax.top_k order)
__device__ inline bool gt(ull ka, int na, ull kb, int nb) {
    return (ka > kb) || (ka == kb && na < nb);
}

// in-wave bitonic sort of 64 (key,node) pairs, descending by gt. zero barriers.
__device__ inline void wsort64(ull& k, int& n, int lane) {
    for (int k2 = 2; k2 <= 64; k2 <<= 1) {
        for (int j = k2 >> 1; j; j >>= 1) {
            ull ok = __shfl_xor(k, j, 64);
            int on = __shfl_xor(n, j, 64);
            bool isLow = (lane & j) == 0;
            bool d = (k2 == 64) || ((lane & k2) == 0);
            bool wantMax = (d == isLow);
            if (wantMax == gt(ok, on, k, n)) { k = ok; n = on; }
        }
    }
}
// in-wave bitonic merge (input bitonic), descending by gt
__device__ inline void wmerge64(ull& k, int& n, int lane) {
    for (int j = 32; j; j >>= 1) {
        ull ok = __shfl_xor(k, j, 64);
        int on = __shfl_xor(n, j, 64);
        bool wantMax = (lane & j) == 0;
        if (wantMax == gt(ok, on, k, n)) { k = ok; n = on; }
    }
}

// -------------------- init: norms + state reset + seeding (fused) --------------------

__global__ __launch_bounds__(256)
void k_init(const float* __restrict__ es, const int* __restrict__ seeds,
            double* __restrict__ inv_norm, int* __restrict__ known,
            unsigned* __restrict__ cate, unsigned* __restrict__ nbr) {
    __shared__ int sn[CC * SS];
    int tid = threadIdx.x, wave = tid >> 6, lane = tid & 63;
    if (tid < CC * SS) sn[tid] = seeds[tid];
    __syncthreads();
    int n = blockIdx.x * 4 + wave;
    if (n >= NN) return;
    float a = es[(long)n * DD + lane];
    float b = es[(long)n * DD + 64 + lane];
    double p = (double)a * (double)a + (double)b * (double)b;
    for (int o = 32; o > 0; o >>= 1) p += __shfl_xor(p, o, 64);
    unsigned bits = 0;
    #pragma unroll
    for (int j = 0; j < 4; ++j) {
        int idx = lane * 4 + j;
        if (sn[idx] == n) bits |= 1u << (idx >> 4);   // class = idx/SS
    }
    for (int o = 32; o > 0; o >>= 1) bits |= __shfl_xor(bits, o, 64);
    if (lane == 0) {
        inv_norm[n] = 1.0 / (sqrt(p) + 1e-8);
        known[n] = bits ? 0 : INF_STAMP;   // seeds: known since iteration 0
        cate[n] = bits;
        nbr[n] = 0;
    }
}

// ------------- fused: memory step (blocks 0..15) + edge pass (rest) -------------

__global__ __launch_bounds__(256)
void k_memedge(const float* __restrict__ es, const float* __restrict__ Wm,
               const int* __restrict__ seeds, const int* __restrict__ last,
               double* __restrict__ hx, double* __restrict__ hxn,
               float* __restrict__ out, int* __restrict__ cnt,
               const int* __restrict__ edge, const unsigned* __restrict__ cate,
               unsigned* __restrict__ nbr, int t) {
    __shared__ float  inp[KK][DD + 1];
    __shared__ int    rowS[KK];
    __shared__ double q[DD], lg[KK], sr[KK], pre[DD], red[DD];
    int tid = threadIdx.x;

    if (blockIdx.x >= CC) {
        long e = (long)(blockIdx.x - CC) * 256 + tid;
        if (e < EE) {
            int s = edge[e];
            unsigned m = cate[s];
            if (m) atomicOr(&nbr[edge[EE + e]], m);
        }
        return;
    }

    int c = blockIdx.x;
    if (tid == 0) cnt[c * CNT_STRIDE] = 0;
    int k = (t == 0) ? SS : KK;
    if (tid < KK) {
        lg[tid] = -1.0e308;
        if (tid < k) rowS[tid] = (t == 0) ? seeds[c * SS + tid] : last[c * KK + tid];
    }
    __syncthreads();
    for (int i = tid; i < k * DD; i += 256)
        inp[i >> 7][i & 127] = es[(long)rowS[i >> 7] * DD + (i & 127)];
    __syncthreads();
    if (tid < DD) {
        if (t == 0) {
            double s = 0;
            for (int j = 0; j < k; ++j) s += (double)inp[j][tid];
            q[tid] = s / (double)k;
        } else {
            q[tid] = hx[c * DD + tid];
        }
    }
    __syncthreads();
    if (tid < k) {
        double s = 0;
        for (int i = 0; i < DD; ++i) s += (double)inp[tid][i] * q[i];
        lg[tid] = s / sqrt((double)DD);
    }
    __syncthreads();
    if (tid < KK) sr[tid] = lg[tid];
    __syncthreads();
    for (int st = 32; st > 0; st >>= 1) {
        if (tid < st) sr[tid] = fmax(sr[tid], sr[tid + st]);
        __syncthreads();
    }
    double mx = sr[0];
    __syncthreads();
    if (tid < KK) {
        double e = (tid < k) ? exp(lg[tid] - mx) : 0.0;
        lg[tid] = e; sr[tid] = e;
    }
    __syncthreads();
    for (int st = 32; st > 0; st >>= 1) {
        if (tid < st) sr[tid] += sr[tid + st];
        __syncthreads();
    }
    double sm = sr[0];
    __syncthreads();
    if (tid < KK) lg[tid] /= sm;
    __syncthreads();
    if (tid < DD) {
        double ctx = 0;
        for (int j = 0; j < k; ++j) ctx += lg[j] * (double)inp[j][tid];
        pre[tid] = (t == 0) ? ctx : (ctx + q[tid]);
    }
    __syncthreads();
    double h = 0;
    if (tid < DD) {
        for (int i = 0; i < DD; ++i) h += pre[i] * (double)Wm[i * DD + tid];
        h = tanh(h);
        red[tid] = h * h;
    }
    __syncthreads();
    for (int st = 64; st > 0; st >>= 1) {
        if (tid < st) red[tid] += red[tid + st];
        __syncthreads();
    }
    if (tid < DD) {
        double inv = 1.0 / (sqrt(red[0]) + 1e-8);
        hx[c * DD + tid] = h;
        hxn[c * DD + tid] = h * inv;
        out[2 * NIT * CC * KK + t * CC * DD + c * DD + tid] = (float)h;  // hxes
    }
}

// -------------------- candidate scoring: block-aggregated, thread-per-pair --------------------

__global__ __launch_bounds__(256)
void k_cand(const float* __restrict__ es, const double* __restrict__ inv_norm,
            const int* __restrict__ known, const unsigned* __restrict__ nbr,
            const double* __restrict__ hxn,
            int* __restrict__ cnt, int* __restrict__ cidx,
            ull* __restrict__ ckey, int cap, int t) {
    __shared__ int    pair[CHUNK * CC];   // packed (ln<<12)|(rank<<4)|c, 16KB
    __shared__ double hxnL[CC * 129];     // padded hxn, 16.5KB
    __shared__ int    lcnt[CC], base[CC], npair;
    int tid = threadIdx.x;

    for (int i = tid; i < CC * DD; i += 256)
        hxnL[(i >> 7) * 129 + (i & 127)] = hxn[i];
    if (tid < CC) lcnt[tid] = 0;
    if (tid == 0) npair = 0;
    __syncthreads();

    int n = blockIdx.x * CHUNK + tid;
    unsigned m = 0;
    if (n < NN && known[n] > t) m = nbr[n];   // stamp > t  <=>  unknown at iter t
    while (m) {
        int c = __ffs(m) - 1;
        m &= m - 1;
        int r = atomicAdd(&lcnt[c], 1);
        int p = atomicAdd(&npair, 1);
        pair[p] = (tid << 12) | (r << 4) | c;
    }
    __syncthreads();

    if (tid < CC && lcnt[tid] > 0)
        base[tid] = atomicAdd(&cnt[tid * CNT_STRIDE], lcnt[tid]);
    __syncthreads();

    int np = npair;
    for (int t2 = tid; t2 < np; t2 += 256) {
        int pk = pair[t2];
        int c = pk & 15, r = (pk >> 4) & 255, ln = pk >> 12;
        int nn = blockIdx.x * CHUNK + ln;
        const float4* row = (const float4*)(es + (long)nn * DD);
        const double* h = &hxnL[c * 129];
        double s = 0;
        #pragma unroll
        for (int i = 0; i < 32; ++i) {
            float4 v = row[i];
            s += (double)v.x * h[4 * i + 0] + (double)v.y * h[4 * i + 1]
               + (double)v.z * h[4 * i + 2] + (double)v.w * h[4 * i + 3];
        }
        int pos = base[c] + r;
        if (pos < cap) {
            cidx[(long)c * cap + pos] = nn;
            ckey[(long)c * cap + pos] = ordkey(s * inv_norm[nn]);
        }
    }
}

// ---- stage A: 32 blocks/class, per-slice exact top-64 (in-wave sorts + LDS tree) ----
// no cross-block sync: the dispatch boundary is the (single, cheap) publish point

__global__ __launch_bounds__(256)
void k_top(const int* __restrict__ cnt, const int* __restrict__ cidx,
           const ull* __restrict__ ckey, int cap,
           ull* __restrict__ tkey, int* __restrict__ tnode) {
    __shared__ ull ks[SLMAX];
    __shared__ int ns[SLMAX];
    int c = blockIdx.x / NB, b = blockIdx.x % NB;
    int tid = threadIdx.x, wave = tid >> 6, lane = tid & 63;
    int count = min(cnt[c * CNT_STRIDE], cap);
    int per = (count + NB - 1) / NB;
    int start = b * per;
    int m2 = min(per, count - start);
    int sl = 64;
    while (sl < per) sl <<= 1;
    int nruns = sl >> 6;
    // sort each 64-run inside one wave (registers, no barriers)
    for (int r = wave; r < nruns; r += 4) {
        int i = (r << 6) + lane;
        ull k; int n;
        if (i < m2) { k = ckey[(long)c * cap + start + i];
                      n = cidx[(long)c * cap + start + i]; }
        else        { k = 0ULL; n = 0x7FFFFFFF; }
        wsort64(k, n, lane);
        ks[i] = k; ns[i] = n;
    }
    __syncthreads();
    // merge tree: each pair handled by one wave; winner written over run A
    for (int step = 1; step < nruns; step <<= 1) {
        int npair2 = nruns / (2 * step);
        for (int pr = wave; pr < npair2; pr += 4) {
            int ra = pr * 2 * step, rb = ra + step;
            ull ka = ks[(ra << 6) + lane];       int na = ns[(ra << 6) + lane];
            ull kb = ks[(rb << 6) + 63 - lane];  int nb2 = ns[(rb << 6) + 63 - lane];
            if (gt(kb, nb2, ka, na)) { ka = kb; na = nb2; }   // bitonic split
            wmerge64(ka, na, lane);
            ks[(ra << 6) + lane] = ka; ns[(ra << 6) + lane] = na;
        }
        __syncthreads();
    }
    if (tid < KK) {
        tkey[(long)c * MM + b * KK + tid] = ks[tid];
        tnode[(long)c * MM + b * KK + tid] = ns[tid];
    }
}

// ---- stage B: block-wide stage of 32 sorted runs + tree merge -> exact top-64;
// ---- apply updates + write outputs ----

__global__ __launch_bounds__(256)
void k_mergeupd(const int* __restrict__ cnt,
                const ull* __restrict__ tkey, const int* __restrict__ tnode,
                int* __restrict__ known, const unsigned* __restrict__ nbr,
                unsigned* __restrict__ cate, int* __restrict__ last,
                float* __restrict__ out, int cap, int t) {
    __shared__ ull ks[MM];
    __shared__ int ns[MM];
    int c = blockIdx.x, tid = threadIdx.x, wave = tid >> 6, lane = tid & 63;
    for (int i = tid; i < MM; i += 256) {
        ks[i] = tkey[(long)c * MM + i];
        ns[i] = tnode[(long)c * MM + i];
    }
    __syncthreads();
    for (int step = 1; step < NB; step <<= 1) {
        int npair2 = NB / (2 * step);
        for (int pr = wave; pr < npair2; pr += 4) {
            int ra = pr * 2 * step, rb = ra + step;
            ull ka = ks[(ra << 6) + lane];       int na = ns[(ra << 6) + lane];
            ull kb = ks[(rb << 6) + 63 - lane];  int nb2 = ns[(rb << 6) + 63 - lane];
            if (gt(kb, nb2, ka, na)) { ka = kb; na = nb2; }
            wmerge64(ka, na, lane);
            ks[(ra << 6) + lane] = ka; ns[(ra << 6) + lane] = na;
        }
        __syncthreads();
    }
    int count = min(cnt[c * CNT_STRIDE], cap);
    int nsel = min(count, KK);
    if (tid < KK && tid < nsel) {
        int n = ns[tid];
        out[t * CC * KK + c * KK + tid] = (float)keyord(ks[tid]);        // outs
        out[NIT * CC * KK + t * CC * KK + c * KK + tid] = (float)n;      // exps
        last[c * KK + tid] = n;
        known[n] = t + 1;                 // stamp invisible to this iteration's tests
        atomicOr(&cate[n], 1u << c);
    }
    // fill path: lowest-index invalid nodes, prob=-1e9. stamp test sees only
    // pre-iteration state -> race-free vs concurrent t+1 stamps (== reference).
    if (tid == 0 && nsel < KK) {
        int r = nsel;
        for (int n = 0; n < NN && r < KK; ++n) {
            bool valid = ((nbr[n] >> c) & 1u) && (known[n] > t);
            if (!valid) {
                out[t * CC * KK + c * KK + r] = -1e9f;
                out[NIT * CC * KK + t * CC * KK + c * KK + r] = (float)n;
                last[c * KK + r] = n;
                known[n] = t + 1;
                atomicOr(&cate[n], 1u << c);
                ++r;
            }
        }
    }
}

// -------------------- host launcher --------------------

extern "C" void kernel_launch(void* const* d_in, const int* in_sizes, int n_in,
                              void* d_out, int out_size, void* d_ws, size_t ws_size,
                              hipStream_t stream) {
    const float* es    = (const float*)d_in[0];
    const int*   edge  = (const int*)d_in[1];
    const int*   seeds = (const int*)d_in[2];
    const float* W     = (const float*)d_in[3];
    float* out = (float*)d_out;

    char* p = (char*)d_ws;
    auto alloc = [&](size_t bytes) -> char* {
        char* r = p;
        p += (bytes + 255) & ~(size_t)255;
        return r;
    };
    double*   inv_norm = (double*)alloc((size_t)NN * 8);
    int*      known    = (int*)alloc((size_t)NN * 4);
    unsigned* cate     = (unsigned*)alloc((size_t)NN * 4);
    unsigned* nbr      = (unsigned*)alloc((size_t)NN * 4);
    double*   hx       = (double*)alloc(CC * DD * 8);
    double*   hxn      = (double*)alloc(CC * DD * 8);
    int*      last     = (int*)alloc(CC * KK * 4);
    int*      cnt      = (int*)alloc(CC * CNT_STRIDE * 4);
    ull*      tkey     = (ull*)alloc((size_t)CC * MM * 8);
    int*      tnode    = (int*)alloc((size_t)CC * MM * 4);
    size_t used = (size_t)(p - (char*)d_ws);
    size_t rem = (ws_size > used + 8192) ? (ws_size - used - 8192) : 0;
    long capl = (long)(rem / (CC * 12));
    if (capl > NN) capl = NN;
    if (capl < 1) capl = 1;
    int cap = (int)capl;
    int*    cidx = (int*)alloc((size_t)CC * cap * 4);
    ull*    ckey = (ull*)alloc((size_t)CC * cap * 8);

    k_init<<<(NN + 3) / 4, 256, 0, stream>>>(es, seeds, inv_norm, known, cate, nbr);

    for (int t = 0; t < NIT; ++t) {
        k_memedge<<<CC + EB, 256, 0, stream>>>(es, W, seeds, last, hx, hxn, out,
                                               cnt, edge, cate, nbr, t);
        k_cand<<<NCH, 256, 0, stream>>>(es, inv_norm, known, nbr, hxn,
                                        cnt, cidx, ckey, cap, t);
        k_top<<<CC * NB, 256, 0, stream>>>(cnt, cidx, ckey, cap, tkey, tnode);
        k_mergeupd<<<CC, 256, 0, stream>>>(cnt, tkey, tnode, known, nbr,
                                           cate, last, out, cap, t);
    }
}